// Round 2
// baseline (231.299 us; speedup 1.0000x reference)
//
#include <hip/hip_runtime.h>
#include <stdint.h>

#define N_PROP 100000
#define N_LAB  256
#define NW     8                      // 256 bits / 32
#define CHUNK  256
#define NCHUNK 391                    // ceil(100000/256)
#define N_PAD  (NCHUNK * CHUNK)       // 100096

// d_ws byte offsets
#define OFF_MASKS   0
#define OFF_CHUNKOR (N_PAD * NW * 4)                   // 3,203,072
#define OFF_TPIDX   (OFF_CHUNKOR + NCHUNK * NW * 4)    // +12,512
#define OFF_TPCONF  (OFF_TPIDX + N_LAB * 4)
#define OFF_TPCNT   (OFF_TPCONF + N_LAB * 4)
#define OFF_RANK    (OFF_TPCNT + 16)

// ---------------------------------------------------------------------------
// Kernel 1: per-proposal 256-bit IoU>0.5 masks + per-chunk OR. Also zeroes the
// rank counters (must be re-zeroed every call; ws is not re-poisoned).
// ---------------------------------------------------------------------------
__global__ __launch_bounds__(256) void k_masks(
    const float* __restrict__ prop, const float* __restrict__ lab,
    uint32_t* __restrict__ masks, uint32_t* __restrict__ chunkOR,
    int* __restrict__ rank) {
  __shared__ float s_bmin[N_LAB], s_bmax[N_LAB], s_blen[N_LAB];
  __shared__ uint32_t s_or[NW];
  const int t = threadIdx.x;
  if (t < NW) s_or[t] = 0u;
  {
    const float bmn = lab[2 * t], bmx = lab[2 * t + 1];
    s_bmin[t] = bmn; s_bmax[t] = bmx; s_blen[t] = bmx - bmn;
  }
  if (blockIdx.x == 0) rank[t] = 0;
  __syncthreads();

  const int i = blockIdx.x * 256 + t;
  uint32_t m[NW];
#pragma unroll
  for (int w = 0; w < NW; ++w) m[w] = 0u;

  if (i < N_PROP) {
    const float ps = prop[3 * i + 1], pe = prop[3 * i + 2];
    // exact reference op order: div by FPS, min/max, clip, union, IEEE div
    const float amin = ps / 25.0f;
    const float amax = pe / 25.0f;
    const float alen = amax - amin;
    for (int j = 0; j < N_LAB; ++j) {
      float inter = fminf(amax, s_bmax[j]) - fmaxf(amin, s_bmin[j]);
      inter = fmaxf(inter, 0.0f);
      const float uni = (alen - inter) + s_blen[j];
      const float iou = inter / uni;
      if (iou > 0.5f) m[j >> 5] |= (1u << (j & 31));
    }
  }

  uint4* mp = reinterpret_cast<uint4*>(&masks[(size_t)i * NW]);
  mp[0] = make_uint4(m[0], m[1], m[2], m[3]);
  mp[1] = make_uint4(m[4], m[5], m[6], m[7]);

  uint32_t any = 0u;
#pragma unroll
  for (int w = 0; w < NW; ++w) any |= m[w];
  if (any) {
#pragma unroll
    for (int w = 0; w < NW; ++w)
      if (m[w]) atomicOr(&s_or[w], m[w]);
  }
  __syncthreads();
  if (t < NW) chunkOR[blockIdx.x * NW + t] = s_or[t];
}

// ---------------------------------------------------------------------------
// Kernel 2: exact sequential greedy scan, single wave (64 lanes).
// Reference semantics: each proposal is evaluated EXACTLY ONCE, in index
// order; if its mask intersects ~detected it claims the FIRST such label and
// is a TP (done — it never claims a second label). Hence <=256 TPs.
// Chunk-OR prefilter via ballot (valid since detected only grows, so a chunk
// with no pending bits stays clean); flagged chunks drained register-resident
// with a consumed-lane clear so each proposal is processed at most once.
// ---------------------------------------------------------------------------
__global__ __launch_bounds__(64) void k_scan(
    const uint32_t* __restrict__ masks, const uint32_t* __restrict__ chunkOR,
    const float* __restrict__ prop,
    int* __restrict__ tp_idx, float* __restrict__ tp_conf,
    int* __restrict__ tp_cnt) {
  const int lane = threadIdx.x;
  uint32_t D[NW];
#pragma unroll
  for (int w = 0; w < NW; ++w) D[w] = 0u;
  int T = 0;
  int c = 0;
  while (c < NCHUNK) {
    const int cc = c + lane;
    uint32_t f = 0u;
    if (cc < NCHUNK) {
      const uint4* q = reinterpret_cast<const uint4*>(&chunkOR[(size_t)cc * NW]);
      const uint4 a = q[0], b = q[1];
      f = (a.x & ~D[0]) | (a.y & ~D[1]) | (a.z & ~D[2]) | (a.w & ~D[3]) |
          (b.x & ~D[4]) | (b.y & ~D[5]) | (b.z & ~D[6]) | (b.w & ~D[7]);
    }
    const unsigned long long bal = __ballot(f != 0u);
    if (bal == 0ull) { c += 64; continue; }
    const int fc = c + (__ffsll(bal) - 1);

    // load chunk fc masks: 4 rows x 64 lanes x 8 words, register resident
    uint32_t m[4][NW];
#pragma unroll
    for (int r = 0; r < 4; ++r) {
      const int i = fc * CHUNK + r * 64 + lane;
      const uint4* q = reinterpret_cast<const uint4*>(&masks[(size_t)i * NW]);
      const uint4 a = q[0], b = q[1];
      m[r][0] = a.x; m[r][1] = a.y; m[r][2] = a.z; m[r][3] = a.w;
      m[r][4] = b.x; m[r][5] = b.y; m[r][6] = b.z; m[r][7] = b.w;
    }
    // Pending pots only shrink as D grows, so repeatedly taking the first
    // pending lane processes proposals in ascending index order, and a lane
    // whose pot is empty when reached can never become pending again.
    for (int r = 0; r < 4; ++r) {
      while (true) {
        uint32_t g = 0u;
#pragma unroll
        for (int w = 0; w < NW; ++w) g |= m[r][w] & ~D[w];
        const unsigned long long b2 = __ballot(g != 0u);
        if (b2 == 0ull) break;
        const int l2 = __ffsll(b2) - 1;   // first pending proposal in this row
        uint32_t pot[NW];
#pragma unroll
        for (int w = 0; w < NW; ++w)
          pot[w] = ((uint32_t)__shfl((int)m[r][w], l2)) & ~D[w];
        int j = -1;
#pragma unroll
        for (int w = 0; w < NW; ++w)
          if (j < 0 && pot[w] != 0u) j = w * 32 + (__ffs(pot[w]) - 1);
        D[j >> 5] |= (1u << (j & 31));    // uniform across lanes
        if (lane == l2) {
          const int i = fc * CHUNK + r * 64 + l2;
          if (T < N_LAB) { tp_idx[T] = i; tp_conf[T] = prop[3 * i]; }
          // consume this proposal: it is evaluated exactly once (the fix)
#pragma unroll
          for (int w = 0; w < NW; ++w) m[r][w] = 0u;
        }
        ++T;
      }
    }
    c = fc + 1;  // earlier chunks were clean under a smaller D -> still clean
  }
  if (lane == 0) tp_cnt[0] = (T < N_LAB) ? T : N_LAB;
}

// ---------------------------------------------------------------------------
// Kernel 3: rank of each TP in stable descending-confidence order.
// rank_t = 1 + #{j : conf_j > conf_t  or (conf_j == conf_t and j < idx_t)}
// ---------------------------------------------------------------------------
__global__ __launch_bounds__(256) void k_rank(
    const float* __restrict__ prop, const int* __restrict__ tp_idx,
    const float* __restrict__ tp_conf, const int* __restrict__ tp_cnt,
    int* __restrict__ rank) {
  __shared__ float s_c[N_LAB];
  __shared__ int s_i[N_LAB];
  __shared__ int s_cnt[N_LAB];
  const int t = threadIdx.x;
  const int T = tp_cnt[0];
  if (t < T) { s_c[t] = tp_conf[t]; s_i[t] = tp_idx[t]; }
  s_cnt[t] = 0;
  __syncthreads();

  const int i = blockIdx.x * 256 + t;
  const bool valid = (i < N_PROP);
  const int lane = t & 63;
  float ci = -1.0f;
  if (valid) ci = prop[3 * i];

  for (int u = 0; u < T; ++u) {
    const float cu = s_c[u];
    const int iu = s_i[u];
    const bool pred = valid && ((ci > cu) || ((ci == cu) && (i < iu)));
    const unsigned long long bal = __ballot(pred);
    if (lane == 0 && bal != 0ull) atomicAdd(&s_cnt[u], (int)__popcll(bal));
  }
  __syncthreads();
  if (t < T && s_cnt[t] != 0) atomicAdd(&rank[t], s_cnt[t]);
}

// ---------------------------------------------------------------------------
// Kernel 4: sort <=256 TP ranks (distinct), suffix-max precision, AP sum.
// AP = (1/256) * sum_{i: p_i >= 2} max_{j>=i} (j / p_j), summed in the
// reference's order (rank descending). The rank-1 term is excluded (x[:-1]).
// ---------------------------------------------------------------------------
__global__ __launch_bounds__(256) void k_ap(
    const int* __restrict__ tp_cnt, const int* __restrict__ rank,
    float* __restrict__ out) {
  __shared__ int s_r[N_LAB];
  __shared__ int s_p[N_LAB];
  const int t = threadIdx.x;
  const int T = tp_cnt[0];
  if (t < T) s_r[t] = 1 + rank[t];
  __syncthreads();
  if (t < T) {
    const int rt = s_r[t];
    int pos = 0;
    for (int s = 0; s < T; ++s) pos += (s_r[s] < rt) ? 1 : 0;
    s_p[pos] = rt;  // ranks are distinct -> bijective
  }
  __syncthreads();
  if (t == 0) {
    float m = 0.0f, sum = 0.0f;
    for (int i = T - 1; i >= 0; --i) {
      const float prec = (float)(i + 1) / (float)s_p[i];  // IEEE div, as ref
      m = fmaxf(m, prec);
      if (s_p[i] >= 2) sum += m * 0.00390625f;  // * (1/256), exact scaling
    }
    out[0] = sum;
  }
}

extern "C" void kernel_launch(void* const* d_in, const int* in_sizes, int n_in,
                              void* d_out, int out_size, void* d_ws,
                              size_t ws_size, hipStream_t stream) {
  (void)in_sizes; (void)n_in; (void)out_size; (void)ws_size;
  const float* prop = (const float*)d_in[0];
  const float* lab  = (const float*)d_in[1];
  uint8_t* ws = (uint8_t*)d_ws;
  uint32_t* masks   = (uint32_t*)(ws + OFF_MASKS);
  uint32_t* chunkOR = (uint32_t*)(ws + OFF_CHUNKOR);
  int*      tp_idx  = (int*)(ws + OFF_TPIDX);
  float*    tp_conf = (float*)(ws + OFF_TPCONF);
  int*      tp_cnt  = (int*)(ws + OFF_TPCNT);
  int*      rank    = (int*)(ws + OFF_RANK);
  float*    out     = (float*)d_out;

  k_masks<<<dim3(NCHUNK), dim3(256), 0, stream>>>(prop, lab, masks, chunkOR, rank);
  k_scan <<<dim3(1),      dim3(64),  0, stream>>>(masks, chunkOR, prop, tp_idx, tp_conf, tp_cnt);
  k_rank <<<dim3(NCHUNK), dim3(256), 0, stream>>>(prop, tp_idx, tp_conf, tp_cnt, rank);
  k_ap   <<<dim3(1),      dim3(256), 0, stream>>>(tp_cnt, rank, out);
}

// Round 3
// 194.576 us; speedup vs baseline: 1.1887x; 1.1887x over previous
//
#include <hip/hip_runtime.h>
#include <stdint.h>

#define N_PROP 100000
#define N_LAB  256
#define NW     8                      // 256 bits / 32
#define CHUNK  256
#define NCHUNK 391                    // ceil(100000/256)
#define N_PAD  (NCHUNK * CHUNK)       // 100096

// d_ws byte offsets
#define OFF_MASKS   0
#define OFF_CHUNKOR (N_PAD * NW * 4)                   // 3,203,072
#define OFF_TPIDX   (OFF_CHUNKOR + NCHUNK * NW * 4)    // +12,512
#define OFF_TPCNT   (OFF_TPIDX + N_LAB * 4)
#define OFF_RANK    (OFF_TPCNT + 16)

// ---------------------------------------------------------------------------
// Kernel 1: per-proposal 256-bit IoU>0.5 masks + per-chunk OR. Also zeroes the
// rank counters (ws is not re-poisoned between replays).
// Arithmetic is bit-identical to the reference (IEEE div, same op order).
// ---------------------------------------------------------------------------
__global__ __launch_bounds__(256) void k_masks(
    const float* __restrict__ prop, const float* __restrict__ lab,
    uint32_t* __restrict__ masks, uint32_t* __restrict__ chunkOR,
    int* __restrict__ rank) {
  __shared__ float4 s_lab[N_LAB];     // (bmin, bmax, blen, 0)
  __shared__ uint32_t s_or[NW];
  const int t = threadIdx.x;
  if (t < NW) s_or[t] = 0u;
  {
    const float bmn = lab[2 * t], bmx = lab[2 * t + 1];
    s_lab[t] = make_float4(bmn, bmx, bmx - bmn, 0.0f);
  }
  if (blockIdx.x == 0) rank[t] = 0;
  __syncthreads();

  const int i = blockIdx.x * 256 + t;
  uint32_t m[NW];
#pragma unroll
  for (int w = 0; w < NW; ++w) m[w] = 0u;

  if (i < N_PROP) {
    const float ps = prop[3 * i + 1], pe = prop[3 * i + 2];
    const float amin = ps / 25.0f;
    const float amax = pe / 25.0f;
    const float alen = amax - amin;
#pragma unroll 4
    for (int j = 0; j < N_LAB; ++j) {
      const float4 L = s_lab[j];
      float inter = fminf(amax, L.y) - fmaxf(amin, L.x);
      inter = fmaxf(inter, 0.0f);
      const float uni = (alen - inter) + L.z;
      const float iou = inter / uni;           // IEEE div, as reference
      if (iou > 0.5f) m[j >> 5] |= (1u << (j & 31));
    }
  }

  uint4* mp = reinterpret_cast<uint4*>(&masks[(size_t)i * NW]);
  mp[0] = make_uint4(m[0], m[1], m[2], m[3]);
  mp[1] = make_uint4(m[4], m[5], m[6], m[7]);

  uint32_t any = 0u;
#pragma unroll
  for (int w = 0; w < NW; ++w) any |= m[w];
  if (any) {
#pragma unroll
    for (int w = 0; w < NW; ++w)
      if (m[w]) atomicOr(&s_or[w], m[w]);
  }
  __syncthreads();
  if (t < NW) chunkOR[blockIdx.x * NW + t] = s_or[t];
}

// ---------------------------------------------------------------------------
// Kernel 2: exact sequential greedy scan, single wave.
// Reference semantics: proposals evaluated exactly once, in index order; a
// proposal claims the FIRST label in (mask & ~detected), if any (then done).
// detected only grows => chunk-OR prefilter is sound, and T <= 256 since each
// claim sets a previously-unset bit.
// Latency design: nothing on the per-claim critical path touches global
// memory; each lane computes its own first-pending-bit so the winner
// broadcast is a single __shfl.
// ---------------------------------------------------------------------------
__global__ __launch_bounds__(64) void k_scan(
    const uint32_t* __restrict__ masks, const uint32_t* __restrict__ chunkOR,
    int* __restrict__ tp_idx, int* __restrict__ tp_cnt) {
  const int lane = threadIdx.x;
  uint32_t D[NW];
#pragma unroll
  for (int w = 0; w < NW; ++w) D[w] = 0u;
  int T = 0;
  int c = 0;
  while (c < NCHUNK) {
    const int cc = c + lane;
    uint32_t f = 0u;
    if (cc < NCHUNK) {
      const uint4* q = reinterpret_cast<const uint4*>(&chunkOR[(size_t)cc * NW]);
      const uint4 a = q[0], b = q[1];
      f = (a.x & ~D[0]) | (a.y & ~D[1]) | (a.z & ~D[2]) | (a.w & ~D[3]) |
          (b.x & ~D[4]) | (b.y & ~D[5]) | (b.z & ~D[6]) | (b.w & ~D[7]);
    }
    const unsigned long long bal = __ballot(f != 0u);
    if (bal == 0ull) { c += 64; continue; }
    const int fc = c + (__ffsll(bal) - 1);

    // load chunk fc masks: 4 rows x 64 lanes x 8 words, register resident
    uint32_t m[4][NW];
#pragma unroll
    for (int r = 0; r < 4; ++r) {
      const int i = fc * CHUNK + r * 64 + lane;
      const uint4* q = reinterpret_cast<const uint4*>(&masks[(size_t)i * NW]);
      const uint4 a = q[0], b = q[1];
      m[r][0] = a.x; m[r][1] = a.y; m[r][2] = a.z; m[r][3] = a.w;
      m[r][4] = b.x; m[r][5] = b.y; m[r][6] = b.z; m[r][7] = b.w;
    }
    // Pending sets only shrink as D grows, so repeatedly taking the first
    // pending lane processes proposals in ascending index order; a consumed
    // lane clears its mask (evaluated exactly once).
    for (int r = 0; r < 4; ++r) {
      while (true) {
        // per-lane pending words and own first pending bit
        unsigned long long w0 =
            ((unsigned long long)(m[r][1] & ~D[1]) << 32) | (m[r][0] & ~D[0]);
        unsigned long long w1 =
            ((unsigned long long)(m[r][3] & ~D[3]) << 32) | (m[r][2] & ~D[2]);
        unsigned long long w2 =
            ((unsigned long long)(m[r][5] & ~D[5]) << 32) | (m[r][4] & ~D[4]);
        unsigned long long w3 =
            ((unsigned long long)(m[r][7] & ~D[7]) << 32) | (m[r][6] & ~D[6]);
        int j_i = -1;
        if (w3 != 0ull) j_i = 192 + __ffsll(w3) - 1;
        if (w2 != 0ull) j_i = 128 + __ffsll(w2) - 1;
        if (w1 != 0ull) j_i =  64 + __ffsll(w1) - 1;
        if (w0 != 0ull) j_i =        __ffsll(w0) - 1;
        const unsigned long long b2 = __ballot(j_i >= 0);
        if (b2 == 0ull) break;
        const int l2 = __ffsll(b2) - 1;   // first pending proposal in row
        const int j = __shfl(j_i, l2);    // its claimed label (current D)
        D[j >> 5] |= (1u << (j & 31));    // uniform across lanes
        if (lane == l2) {
          if (T < N_LAB) tp_idx[T] = fc * CHUNK + r * 64 + l2;
#pragma unroll
          for (int w = 0; w < NW; ++w) m[r][w] = 0u;  // consume
        }
        ++T;
      }
    }
    c = fc + 1;  // earlier chunks were clean under a smaller D -> still clean
  }
  if (lane == 0) tp_cnt[0] = (T < N_LAB) ? T : N_LAB;
}

// ---------------------------------------------------------------------------
// Kernel 3: rank of each TP in stable descending-confidence order.
// rank_t = 1 + #{j : conf_j > conf_t or (conf_j == conf_t and j < idx_t)}
// ---------------------------------------------------------------------------
__global__ __launch_bounds__(256) void k_rank(
    const float* __restrict__ prop, const int* __restrict__ tp_idx,
    const int* __restrict__ tp_cnt, int* __restrict__ rank) {
  __shared__ float s_c[N_LAB];
  __shared__ int s_i[N_LAB];
  __shared__ int s_cnt[N_LAB];
  const int t = threadIdx.x;
  const int T = tp_cnt[0];
  if (t < T) {
    const int it = tp_idx[t];
    s_i[t] = it;
    s_c[t] = prop[3 * it];              // parallel conf gather (L2-hit)
  }
  s_cnt[t] = 0;
  __syncthreads();

  const int i = blockIdx.x * 256 + t;
  const bool valid = (i < N_PROP);
  const int lane = t & 63;
  float ci = -1.0f;
  if (valid) ci = prop[3 * i];

  for (int u = 0; u < T; ++u) {
    const float cu = s_c[u];
    const int iu = s_i[u];
    const bool pred = valid && ((ci > cu) || ((ci == cu) && (i < iu)));
    const unsigned long long bal = __ballot(pred);
    if (lane == 0 && bal != 0ull) atomicAdd(&s_cnt[u], (int)__popcll(bal));
  }
  __syncthreads();
  if (t < T && s_cnt[t] != 0) atomicAdd(&rank[t], s_cnt[t]);
}

// ---------------------------------------------------------------------------
// Kernel 4: sort <=256 TP ranks (distinct), suffix-max precision, AP sum.
// AP = (1/256) * sum_{i: p_i >= 2} max_{j>=i} (j / p_j), accumulated in the
// reference's order (rank descending); rank-1 term excluded (x[:-1] quirk).
// ---------------------------------------------------------------------------
__global__ __launch_bounds__(256) void k_ap(
    const int* __restrict__ tp_cnt, const int* __restrict__ rank,
    float* __restrict__ out) {
  __shared__ int s_r[N_LAB];
  __shared__ int s_p[N_LAB];
  const int t = threadIdx.x;
  const int T = tp_cnt[0];
  if (t < T) s_r[t] = 1 + rank[t];
  __syncthreads();
  if (t < T) {
    const int rt = s_r[t];
    int pos = 0;
    for (int s = 0; s < T; ++s) pos += (s_r[s] < rt) ? 1 : 0;
    s_p[pos] = rt;  // ranks are distinct -> bijective
  }
  __syncthreads();
  if (t == 0) {
    float m = 0.0f, sum = 0.0f;
    for (int i = T - 1; i >= 0; --i) {
      const float prec = (float)(i + 1) / (float)s_p[i];  // IEEE div, as ref
      m = fmaxf(m, prec);
      if (s_p[i] >= 2) sum += m * 0.00390625f;  // * (1/256), exact
    }
    out[0] = sum;
  }
}

extern "C" void kernel_launch(void* const* d_in, const int* in_sizes, int n_in,
                              void* d_out, int out_size, void* d_ws,
                              size_t ws_size, hipStream_t stream) {
  (void)in_sizes; (void)n_in; (void)out_size; (void)ws_size;
  const float* prop = (const float*)d_in[0];
  const float* lab  = (const float*)d_in[1];
  uint8_t* ws = (uint8_t*)d_ws;
  uint32_t* masks   = (uint32_t*)(ws + OFF_MASKS);
  uint32_t* chunkOR = (uint32_t*)(ws + OFF_CHUNKOR);
  int*      tp_idx  = (int*)(ws + OFF_TPIDX);
  int*      tp_cnt  = (int*)(ws + OFF_TPCNT);
  int*      rank    = (int*)(ws + OFF_RANK);
  float*    out     = (float*)d_out;

  k_masks<<<dim3(NCHUNK), dim3(256), 0, stream>>>(prop, lab, masks, chunkOR, rank);
  k_scan <<<dim3(1),      dim3(64),  0, stream>>>(masks, chunkOR, tp_idx, tp_cnt);
  k_rank <<<dim3(NCHUNK), dim3(256), 0, stream>>>(prop, tp_idx, tp_cnt, rank);
  k_ap   <<<dim3(1),      dim3(256), 0, stream>>>(tp_cnt, rank, out);
}

// Round 4
// 163.441 us; speedup vs baseline: 1.4152x; 1.1905x over previous
//
#include <hip/hip_runtime.h>
#include <stdint.h>

#define N_PROP 100000
#define N_LAB  256
#define NW     8                      // 256 bits / 32
#define CHUNK  256
#define NCHUNK 391                    // ceil(100000/256)
#define N_PAD  (NCHUNK * CHUNK)       // 100096

// d_ws byte offsets (all 16-aligned)
#define OFF_MASKS   0
#define OFF_CHUNKOR (N_PAD * NW * 4)                   // 3,203,072
#define OFF_TPIDX   (OFF_CHUNKOR + NCHUNK * NW * 4)    // +12,512
#define OFF_TPCNT   (OFF_TPIDX + N_LAB * 4)
#define OFF_KEYS    (OFF_TPCNT + 16)                   // 256 x u64
#define OFF_HIST    (OFF_KEYS + N_LAB * 8)             // 257 x int

// first pending label from 4 x u64 pending words (-1 if none)
#define FIRST_PEND(j_i, w0, w1, w2, w3)         \
  {                                             \
    j_i = -1;                                   \
    if (w3) j_i = 192 + (__ffsll(w3) - 1);      \
    if (w2) j_i = 128 + (__ffsll(w2) - 1);      \
    if (w1) j_i = 64 + (__ffsll(w1) - 1);       \
    if (w0) j_i = (__ffsll(w0) - 1);            \
  }

// ---------------------------------------------------------------------------
// Kernel 1: per-proposal 256-bit IoU>0.5 masks + per-chunk OR. Block 0 also
// zeroes the global histogram (ws is not re-poisoned between replays).
// Arithmetic is bit-identical to the reference (IEEE div, same op order).
// ---------------------------------------------------------------------------
__global__ __launch_bounds__(256) void k_masks(
    const float* __restrict__ prop, const float* __restrict__ lab,
    uint32_t* __restrict__ masks, uint32_t* __restrict__ chunkOR,
    int* __restrict__ hist) {
  __shared__ float4 s_lab[N_LAB];     // (bmin, bmax, blen, 0)
  __shared__ uint32_t s_or[NW];
  const int t = threadIdx.x;
  if (t < NW) s_or[t] = 0u;
  {
    const float bmn = lab[2 * t], bmx = lab[2 * t + 1];
    s_lab[t] = make_float4(bmn, bmx, bmx - bmn, 0.0f);
  }
  if (blockIdx.x == 0) {
    hist[t] = 0;
    if (t == 0) hist[N_LAB] = 0;
  }
  __syncthreads();

  const int i = blockIdx.x * 256 + t;
  uint32_t m[NW];
#pragma unroll
  for (int w = 0; w < NW; ++w) m[w] = 0u;

  if (i < N_PROP) {
    const float ps = prop[3 * i + 1], pe = prop[3 * i + 2];
    const float amin = ps / 25.0f;
    const float amax = pe / 25.0f;
    const float alen = amax - amin;
#pragma unroll 4
    for (int j = 0; j < N_LAB; ++j) {
      const float4 L = s_lab[j];
      float inter = fminf(amax, L.y) - fmaxf(amin, L.x);
      inter = fmaxf(inter, 0.0f);
      const float uni = (alen - inter) + L.z;
      const float iou = inter / uni;           // IEEE div, as reference
      if (iou > 0.5f) m[j >> 5] |= (1u << (j & 31));
    }
  }

  uint4* mp = reinterpret_cast<uint4*>(&masks[(size_t)i * NW]);
  mp[0] = make_uint4(m[0], m[1], m[2], m[3]);
  mp[1] = make_uint4(m[4], m[5], m[6], m[7]);

  uint32_t any = 0u;
#pragma unroll
  for (int w = 0; w < NW; ++w) any |= m[w];
  if (any) {
#pragma unroll
    for (int w = 0; w < NW; ++w)
      if (m[w]) atomicOr(&s_or[w], m[w]);
  }
  __syncthreads();
  if (t < NW) chunkOR[blockIdx.x * NW + t] = s_or[t];
}

// ---------------------------------------------------------------------------
// Kernel 2: exact sequential greedy scan, single wave.
// Reference semantics: proposals evaluated exactly once, in index order; a
// proposal claims the FIRST label in (mask & ~detected), if any (then done).
// detected only grows => (a) the chunk-OR prefilter is sound, (b) a lane with
// empty pending at row start can never become pending => ONE ballot per row
// gives the exact visit set, visited in ascending lane order. Each lane
// incrementally maintains pending = mask & ~D; the only cross-lane op per
// claim is a single readlane of the winner's first-pending label.
// T <= 256 structurally (each claim sets a previously-unset bit of D).
// ---------------------------------------------------------------------------
__global__ __launch_bounds__(64) void k_scan(
    const uint32_t* __restrict__ masks, const uint32_t* __restrict__ chunkOR,
    int* __restrict__ tp_idx, int* __restrict__ tp_cnt) {
  const int lane = threadIdx.x;
  uint32_t D[NW];
#pragma unroll
  for (int w = 0; w < NW; ++w) D[w] = 0u;
  int T = 0;
  int c = 0;
  while (c < NCHUNK) {
    const int cc = c + lane;
    uint32_t f = 0u;
    if (cc < NCHUNK) {
      const uint4* q = reinterpret_cast<const uint4*>(&chunkOR[(size_t)cc * NW]);
      const uint4 a = q[0], b = q[1];
      f = (a.x & ~D[0]) | (a.y & ~D[1]) | (a.z & ~D[2]) | (a.w & ~D[3]) |
          (b.x & ~D[4]) | (b.y & ~D[5]) | (b.z & ~D[6]) | (b.w & ~D[7]);
    }
    const unsigned long long bal = __ballot(f != 0u);
    if (bal == 0ull) { c += 64; continue; }
    const int fc = c + (__ffsll(bal) - 1);

    // load chunk fc masks: 4 rows x 64 lanes x 8 words, register resident
    uint32_t m[4][NW];
#pragma unroll
    for (int r = 0; r < 4; ++r) {
      const int i = fc * CHUNK + r * 64 + lane;
      const uint4* q = reinterpret_cast<const uint4*>(&masks[(size_t)i * NW]);
      const uint4 a = q[0], b = q[1];
      m[r][0] = a.x; m[r][1] = a.y; m[r][2] = a.z; m[r][3] = a.w;
      m[r][4] = b.x; m[r][5] = b.y; m[r][6] = b.z; m[r][7] = b.w;
    }

    for (int r = 0; r < 4; ++r) {
      // per-lane pending words under current D
      unsigned long long w0 =
          ((unsigned long long)(m[r][1] & ~D[1]) << 32) | (m[r][0] & ~D[0]);
      unsigned long long w1 =
          ((unsigned long long)(m[r][3] & ~D[3]) << 32) | (m[r][2] & ~D[2]);
      unsigned long long w2 =
          ((unsigned long long)(m[r][5] & ~D[5]) << 32) | (m[r][4] & ~D[4]);
      unsigned long long w3 =
          ((unsigned long long)(m[r][7] & ~D[7]) << 32) | (m[r][6] & ~D[6]);
      int j_i;
      FIRST_PEND(j_i, w0, w1, w2, w3);
      unsigned long long rbal = __ballot(j_i >= 0);   // exact visit set
      while (rbal != 0ull) {
        const int l = __ffsll(rbal) - 1;              // ascending index order
        rbal &= rbal - 1;
        const int j = __builtin_amdgcn_readlane(j_i, l);  // winner's label
        if (j >= 0) {                                 // uniform branch
          D[j >> 5] |= (1u << (j & 31));
          if (lane == 0) tp_idx[T] = fc * CHUNK + r * 64 + l;
          ++T;                                        // T<=256 structurally
          // clear claimed bit from every lane's pending, recompute own first
          const unsigned long long bm = 1ull << (j & 63);
          const int q = j >> 6;
          w0 &= (q == 0) ? ~bm : ~0ull;
          w1 &= (q == 1) ? ~bm : ~0ull;
          w2 &= (q == 2) ? ~bm : ~0ull;
          w3 &= (q == 3) ? ~bm : ~0ull;
          FIRST_PEND(j_i, w0, w1, w2, w3);
        }
      }
    }
    c = fc + 1;  // earlier chunks were clean under a smaller D -> still clean
  }
  if (lane == 0) tp_cnt[0] = (T < N_LAB) ? T : N_LAB;
}

// ---------------------------------------------------------------------------
// Kernel 3: build + sort TP priority keys (1 block).
// key = (conf_bits << 32) | (0xFFFFFFFF - idx): larger key = higher priority,
// exactly the reference's stable argsort(-conf) order (conf >= 0 => float
// compare == uint compare on bits; ties broken by lower idx). Pad to 256 with
// UINT64_MAX (real keys can never equal it). Counting sort, O(T) per thread.
// ---------------------------------------------------------------------------
__global__ __launch_bounds__(256) void k_sort(
    const float* __restrict__ prop, const int* __restrict__ tp_idx,
    const int* __restrict__ tp_cnt, unsigned long long* __restrict__ keys) {
  __shared__ unsigned long long s_key[N_LAB];
  __shared__ unsigned long long s_sorted[N_LAB];
  const int t = threadIdx.x;
  int T = tp_cnt[0];
  T = (T < 0) ? 0 : ((T > N_LAB) ? N_LAB : T);
  unsigned long long k = ~0ull;
  if (t < T) {
    const int it = tp_idx[t];
    const unsigned cb = __float_as_uint(prop[3 * it]);
    k = ((unsigned long long)cb << 32) |
        (unsigned long long)(0xFFFFFFFFu - (unsigned)it);
  }
  s_key[t] = k;
  s_sorted[t] = ~0ull;
  __syncthreads();
  int pos = 0;
  for (int s = 0; s < N_LAB; ++s) pos += (s_key[s] < k) ? 1 : 0;
  if (t < T) s_sorted[pos] = k;    // real keys distinct -> bijective
  __syncthreads();
  keys[t] = s_sorted[t];
}

// ---------------------------------------------------------------------------
// Kernel 4: fully parallel rank histogram. For each proposal i, p_i = number
// of sorted TP keys < key_i (8-step lower_bound, fixed trip count). Then
// rank of the TP at sorted position p is 1 + sum_{q>p} hist[q] (kernel 5).
// ---------------------------------------------------------------------------
__global__ __launch_bounds__(256) void k_rank(
    const float* __restrict__ prop, const unsigned long long* __restrict__ keys,
    int* __restrict__ hist) {
  __shared__ unsigned long long s_key[N_LAB];
  __shared__ int s_hist[N_LAB + 1];
  const int t = threadIdx.x;
  s_key[t] = keys[t];
  s_hist[t] = 0;
  if (t == 0) s_hist[N_LAB] = 0;
  __syncthreads();

  const int i = blockIdx.x * 256 + t;
  if (i < N_PROP) {
    const unsigned cb = __float_as_uint(prop[3 * i]);
    const unsigned long long k =
        ((unsigned long long)cb << 32) |
        (unsigned long long)(0xFFFFFFFFu - (unsigned)i);
    int p = 0;
#pragma unroll
    for (int s = 128; s > 0; s >>= 1) {
      const int cand = p + s;
      if (s_key[cand - 1] < k) p = cand;
    }
    atomicAdd(&s_hist[p], 1);
  }
  __syncthreads();
  if (s_hist[t] != 0) atomicAdd(&hist[t], s_hist[t]);
  if (t == 0 && s_hist[N_LAB] != 0) atomicAdd(&hist[N_LAB], s_hist[N_LAB]);
}

// ---------------------------------------------------------------------------
// Kernel 5: integer suffix-sum of hist (exact), ranks in priority order, then
// the AP sum with byte-identical fp ops/order to the previous (bit-exact)
// version: s_p[] = TP ranks ascending; serial loop descending.
// AP = (1/256) * sum_{i: p_i >= 2} max_{j>=i} (j / p_j); rank-1 term excluded.
// ---------------------------------------------------------------------------
__global__ __launch_bounds__(256) void k_ap(
    const int* __restrict__ tp_cnt, const int* __restrict__ hist,
    float* __restrict__ out) {
  __shared__ int s_a[N_LAB + 1];
  __shared__ int s_b[N_LAB + 1];
  __shared__ int s_p[N_LAB];
  const int t = threadIdx.x;
  int T = tp_cnt[0];
  T = (T < 0) ? 0 : ((T > N_LAB) ? N_LAB : T);
  s_a[t] = hist[t];
  if (t == 0) s_a[N_LAB] = hist[N_LAB];
  __syncthreads();
  // suffix sums over 257 entries (Hillis-Steele, ping-pong, ints = exact)
  int* src = s_a;
  int* dst = s_b;
#pragma unroll
  for (int s = 1; s <= N_LAB; s <<= 1) {
    const int v = src[t] + ((t + s <= N_LAB) ? src[t + s] : 0);
    const int v256 = (t == 0) ? src[N_LAB] : 0;
    __syncthreads();
    dst[t] = v;
    if (t == 0) dst[N_LAB] = v256;
    __syncthreads();
    int* tmp = src; src = dst; dst = tmp;
  }
  // TP at sorted position t (ascending priority): rank = 1 + suffix[t+1].
  // Ranks decrease as position increases -> ascending-rank order is reversed.
  if (t < T) s_p[(T - 1) - t] = 1 + src[t + 1];
  __syncthreads();
  if (t == 0) {
    float m = 0.0f, sum = 0.0f;
    for (int i = T - 1; i >= 0; --i) {
      const float prec = (float)(i + 1) / (float)s_p[i];  // IEEE div, as ref
      m = fmaxf(m, prec);
      if (s_p[i] >= 2) sum += m * 0.00390625f;  // * (1/256), exact
    }
    out[0] = sum;
  }
}

extern "C" void kernel_launch(void* const* d_in, const int* in_sizes, int n_in,
                              void* d_out, int out_size, void* d_ws,
                              size_t ws_size, hipStream_t stream) {
  (void)in_sizes; (void)n_in; (void)out_size; (void)ws_size;
  const float* prop = (const float*)d_in[0];
  const float* lab  = (const float*)d_in[1];
  uint8_t* ws = (uint8_t*)d_ws;
  uint32_t* masks  = (uint32_t*)(ws + OFF_MASKS);
  uint32_t* chOR   = (uint32_t*)(ws + OFF_CHUNKOR);
  int*      tp_idx = (int*)(ws + OFF_TPIDX);
  int*      tp_cnt = (int*)(ws + OFF_TPCNT);
  unsigned long long* keys = (unsigned long long*)(ws + OFF_KEYS);
  int*      hist   = (int*)(ws + OFF_HIST);
  float*    out    = (float*)d_out;

  k_masks<<<dim3(NCHUNK), dim3(256), 0, stream>>>(prop, lab, masks, chOR, hist);
  k_scan <<<dim3(1),      dim3(64),  0, stream>>>(masks, chOR, tp_idx, tp_cnt);
  k_sort <<<dim3(1),      dim3(256), 0, stream>>>(prop, tp_idx, tp_cnt, keys);
  k_rank <<<dim3(NCHUNK), dim3(256), 0, stream>>>(prop, keys, hist);
  k_ap   <<<dim3(1),      dim3(256), 0, stream>>>(tp_cnt, hist, out);
}

// Round 6
// 161.230 us; speedup vs baseline: 1.4346x; 1.0137x over previous
//
#include <hip/hip_runtime.h>
#include <stdint.h>

#define N_PROP 100000
#define N_LAB  256
#define NW     8                      // 256 bits / 32
#define CHUNK  256
#define NCHUNK 391                    // ceil(100000/256)
#define N_PAD  (NCHUNK * CHUNK)       // 100096

// d_ws byte offsets (R4 layout)
#define OFF_MASKS   0
#define OFF_CHUNKOR (N_PAD * NW * 4)                   // 3,203,072
#define OFF_TPIDX   (OFF_CHUNKOR + NCHUNK * NW * 4)    // +12,512
#define OFF_TPCNT   (OFF_TPIDX + N_LAB * 4)
#define OFF_KEYS    (OFF_TPCNT + 16)                   // 256 x u64
#define OFF_HIST    (OFF_KEYS + N_LAB * 8)             // 257 x int

// first pending label from 4 x u64 pending words (-1 if none)
#define FIRST_PEND(j_i, w0, w1, w2, w3)         \
  {                                             \
    j_i = -1;                                   \
    if (w3) j_i = 192 + (__ffsll(w3) - 1);      \
    if (w2) j_i = 128 + (__ffsll(w2) - 1);      \
    if (w1) j_i = 64 + (__ffsll(w1) - 1);       \
    if (w0) j_i = (__ffsll(w0) - 1);            \
  }

// ---------------------------------------------------------------------------
// Kernel 1 (R4, unchanged): per-proposal 256-bit IoU>0.5 masks + per-chunk
// OR. Block 0 zeroes the global histogram (ws is not re-poisoned between
// replays). Arithmetic bit-identical to the reference (IEEE div, same order).
// ---------------------------------------------------------------------------
__global__ __launch_bounds__(256) void k_masks(
    const float* __restrict__ prop, const float* __restrict__ lab,
    uint32_t* __restrict__ masks, uint32_t* __restrict__ chunkOR,
    int* __restrict__ hist) {
  __shared__ float4 s_lab[N_LAB];     // (bmin, bmax, blen, 0)
  __shared__ uint32_t s_or[NW];
  const int t = threadIdx.x;
  if (t < NW) s_or[t] = 0u;
  {
    const float bmn = lab[2 * t], bmx = lab[2 * t + 1];
    s_lab[t] = make_float4(bmn, bmx, bmx - bmn, 0.0f);
  }
  if (blockIdx.x == 0) {
    hist[t] = 0;
    if (t == 0) hist[N_LAB] = 0;
  }
  __syncthreads();

  const int i = blockIdx.x * 256 + t;
  uint32_t m[NW];
#pragma unroll
  for (int w = 0; w < NW; ++w) m[w] = 0u;

  if (i < N_PROP) {
    const float ps = prop[3 * i + 1], pe = prop[3 * i + 2];
    const float amin = ps / 25.0f;
    const float amax = pe / 25.0f;
    const float alen = amax - amin;
#pragma unroll 4
    for (int j = 0; j < N_LAB; ++j) {
      const float4 L = s_lab[j];
      float inter = fminf(amax, L.y) - fmaxf(amin, L.x);
      inter = fmaxf(inter, 0.0f);
      const float uni = (alen - inter) + L.z;
      const float iou = inter / uni;           // IEEE div, as reference
      if (iou > 0.5f) m[j >> 5] |= (1u << (j & 31));
    }
  }

  uint4* mp = reinterpret_cast<uint4*>(&masks[(size_t)i * NW]);
  mp[0] = make_uint4(m[0], m[1], m[2], m[3]);
  mp[1] = make_uint4(m[4], m[5], m[6], m[7]);

  uint32_t any = 0u;
#pragma unroll
  for (int w = 0; w < NW; ++w) any |= m[w];
  if (any) {
#pragma unroll
    for (int w = 0; w < NW; ++w)
      if (m[w]) atomicOr(&s_or[w], m[w]);
  }
  __syncthreads();
  if (t < NW) chunkOR[blockIdx.x * NW + t] = s_or[t];
}

// ---------------------------------------------------------------------------
// Kernel 2: exact sequential greedy scan, single wave. R4 control flow
// (proven vs reference), de-scratched: detected bits in NAMED scalars D0..D7
// (select-OR updates), current chunk's 4 rows in NAMED uint4 registers.
// No runtime-indexed local arrays -> no scratch round-trips.
// Claim semantics: proposals evaluated exactly once in index order; a
// proposal claims the first label of (mask & ~detected), if any, then stops.
// ---------------------------------------------------------------------------
#define DRAIN_ROW(BASE, VA, VB)                                             \
  {                                                                         \
    unsigned long long w0 = ((unsigned long long)(VA.y & ~D1) << 32) |      \
                            (unsigned long long)(uint32_t)(VA.x & ~D0);     \
    unsigned long long w1 = ((unsigned long long)(VA.w & ~D3) << 32) |      \
                            (unsigned long long)(uint32_t)(VA.z & ~D2);     \
    unsigned long long w2 = ((unsigned long long)(VB.y & ~D5) << 32) |      \
                            (unsigned long long)(uint32_t)(VB.x & ~D4);     \
    unsigned long long w3 = ((unsigned long long)(VB.w & ~D7) << 32) |      \
                            (unsigned long long)(uint32_t)(VB.z & ~D6);     \
    int j_i;                                                                \
    FIRST_PEND(j_i, w0, w1, w2, w3);                                        \
    unsigned long long rbal = __ballot(j_i >= 0);                           \
    while (rbal != 0ull) {                                                  \
      const int l_ = __ffsll(rbal) - 1;                                     \
      rbal &= rbal - 1;                                                     \
      const int j_ = __builtin_amdgcn_readlane(j_i, l_);                    \
      if (j_ >= 0) {                                                        \
        const uint32_t bit_ = 1u << (j_ & 31);                              \
        const int q5_ = j_ >> 5;                                            \
        D0 |= (q5_ == 0) ? bit_ : 0u;  D1 |= (q5_ == 1) ? bit_ : 0u;        \
        D2 |= (q5_ == 2) ? bit_ : 0u;  D3 |= (q5_ == 3) ? bit_ : 0u;        \
        D4 |= (q5_ == 4) ? bit_ : 0u;  D5 |= (q5_ == 5) ? bit_ : 0u;        \
        D6 |= (q5_ == 6) ? bit_ : 0u;  D7 |= (q5_ == 7) ? bit_ : 0u;        \
        const unsigned long long bm_ = 1ull << (j_ & 63);                   \
        const int q6_ = j_ >> 6;                                            \
        w0 &= (q6_ == 0) ? ~bm_ : ~0ull;  w1 &= (q6_ == 1) ? ~bm_ : ~0ull;  \
        w2 &= (q6_ == 2) ? ~bm_ : ~0ull;  w3 &= (q6_ == 3) ? ~bm_ : ~0ull;  \
        FIRST_PEND(j_i, w0, w1, w2, w3);                                    \
        if (lane == 0 && T < N_LAB) tp_idx[T] = (BASE) + l_;                \
        ++T;                                                                \
      }                                                                     \
    }                                                                       \
  }

__global__ __launch_bounds__(64) void k_scan(
    const uint32_t* __restrict__ masks, const uint32_t* __restrict__ chunkOR,
    int* __restrict__ tp_idx, int* __restrict__ tp_cnt) {
  const int lane = threadIdx.x;
  uint32_t D0 = 0, D1 = 0, D2 = 0, D3 = 0, D4 = 0, D5 = 0, D6 = 0, D7 = 0;
  int T = 0;
  int c = 0;
  while (c < NCHUNK) {
    const int cc = c + lane;
    uint32_t f = 0u;
    if (cc < NCHUNK) {
      const uint4* q = reinterpret_cast<const uint4*>(&chunkOR[(size_t)cc * NW]);
      const uint4 a = q[0], b = q[1];
      f = (a.x & ~D0) | (a.y & ~D1) | (a.z & ~D2) | (a.w & ~D3) |
          (b.x & ~D4) | (b.y & ~D5) | (b.z & ~D6) | (b.w & ~D7);
    }
    const unsigned long long bal = __ballot(f != 0u);
    if (bal == 0ull) { c += 64; continue; }
    const int fc = c + (__ffsll(bal) - 1);

    // Load all 4 rows of chunk fc into named registers (loads pipeline, one
    // wait). Rows >= N_PROP are zero-filled in masks[] (k_masks writes all
    // of N_PAD), and fc*CHUNK+192+lane <= 100,095 < N_PAD: always in-bounds.
    const size_t base = (size_t)fc * CHUNK * NW;
    const uint4* qm = reinterpret_cast<const uint4*>(&masks[base]);
    const int l2i = lane * 2;
    const uint4 r0a = qm[l2i],       r0b = qm[l2i + 1];
    const uint4 r1a = qm[128 + l2i], r1b = qm[128 + l2i + 1];
    const uint4 r2a = qm[256 + l2i], r2b = qm[256 + l2i + 1];
    const uint4 r3a = qm[384 + l2i], r3b = qm[384 + l2i + 1];

    DRAIN_ROW(fc * CHUNK + 0,   r0a, r0b);
    DRAIN_ROW(fc * CHUNK + 64,  r1a, r1b);
    DRAIN_ROW(fc * CHUNK + 128, r2a, r2b);
    DRAIN_ROW(fc * CHUNK + 192, r3a, r3b);

    c = fc + 1;  // earlier chunks were clean under a smaller D -> still clean
  }
  if (lane == 0) tp_cnt[0] = (T < N_LAB) ? T : N_LAB;
}

// ---------------------------------------------------------------------------
// Kernel 3 (R4, unchanged): build + sort TP priority keys (1 block).
// key = (conf_bits << 32) | (0xFFFFFFFF - idx): exactly the reference's
// stable argsort(-conf) order. Pad to 256 with UINT64_MAX.
// ---------------------------------------------------------------------------
__global__ __launch_bounds__(256) void k_sort(
    const float* __restrict__ prop, const int* __restrict__ tp_idx,
    const int* __restrict__ tp_cnt, unsigned long long* __restrict__ keys) {
  __shared__ unsigned long long s_key[N_LAB];
  __shared__ unsigned long long s_sorted[N_LAB];
  const int t = threadIdx.x;
  int T = tp_cnt[0];
  T = (T < 0) ? 0 : ((T > N_LAB) ? N_LAB : T);
  unsigned long long k = ~0ull;
  if (t < T) {
    const int it = tp_idx[t];
    const unsigned cb = __float_as_uint(prop[3 * it]);
    k = ((unsigned long long)cb << 32) |
        (unsigned long long)(0xFFFFFFFFu - (unsigned)it);
  }
  s_key[t] = k;
  s_sorted[t] = ~0ull;
  __syncthreads();
  int pos = 0;
  for (int s = 0; s < N_LAB; ++s) pos += (s_key[s] < k) ? 1 : 0;
  if (t < T) s_sorted[pos] = k;    // real keys distinct -> bijective
  __syncthreads();
  keys[t] = s_sorted[t];
}

// ---------------------------------------------------------------------------
// Kernel 4: rank histogram. p_i = #{sorted TP keys < key_i} via EXACT
// lower_bound in [0,256] (9-step guarded power-of-two search — R4's 8-step
// version capped p at 255, misplacing proposals ranked above ALL TPs when
// T==256; that was the 3.05e-5 absmax).
// ---------------------------------------------------------------------------
__global__ __launch_bounds__(256) void k_rank(
    const float* __restrict__ prop, const unsigned long long* __restrict__ keys,
    int* __restrict__ hist) {
  __shared__ unsigned long long s_key[N_LAB];
  __shared__ int s_hist[N_LAB + 1];
  const int t = threadIdx.x;
  s_key[t] = keys[t];
  s_hist[t] = 0;
  if (t == 0) s_hist[N_LAB] = 0;
  __syncthreads();

  const int i = blockIdx.x * 256 + t;
  if (i < N_PROP) {
    const unsigned cb = __float_as_uint(prop[3 * i]);
    const unsigned long long k =
        ((unsigned long long)cb << 32) |
        (unsigned long long)(0xFFFFFFFFu - (unsigned)i);
    int p = 0;
#pragma unroll
    for (int s = 256; s > 0; s >>= 1) {
      const int cand = p + s;
      if (cand <= N_LAB && s_key[cand - 1] < k) p = cand;
    }
    atomicAdd(&s_hist[p], 1);
  }
  __syncthreads();
  if (s_hist[t] != 0) atomicAdd(&hist[t], s_hist[t]);
  if (t == 0 && s_hist[N_LAB] != 0) atomicAdd(&hist[N_LAB], s_hist[N_LAB]);
}

// ---------------------------------------------------------------------------
// Kernel 5 (R4, unchanged): exact integer suffix-sum of hist, ranks in
// priority order, then the AP sum with the proven-bit-exact fp loop.
// AP = (1/256) * sum_{i: p_i >= 2} max_{j>=i} (j / p_j); rank-1 term
// excluded (reference's x[:-1] quirk).
// ---------------------------------------------------------------------------
__global__ __launch_bounds__(256) void k_ap(
    const int* __restrict__ tp_cnt, const int* __restrict__ hist,
    float* __restrict__ out) {
  __shared__ int s_a[N_LAB + 1];
  __shared__ int s_b[N_LAB + 1];
  __shared__ int s_p[N_LAB];
  const int t = threadIdx.x;
  int T = tp_cnt[0];
  T = (T < 0) ? 0 : ((T > N_LAB) ? N_LAB : T);
  s_a[t] = hist[t];
  if (t == 0) s_a[N_LAB] = hist[N_LAB];
  __syncthreads();
  int* src = s_a;
  int* dst = s_b;
#pragma unroll
  for (int s = 1; s <= N_LAB; s <<= 1) {
    const int v = src[t] + ((t + s <= N_LAB) ? src[t + s] : 0);
    const int v256 = (t == 0) ? src[N_LAB] : 0;
    __syncthreads();
    dst[t] = v;
    if (t == 0) dst[N_LAB] = v256;
    __syncthreads();
    int* tmp = src; src = dst; dst = tmp;
  }
  if (t < T) s_p[(T - 1) - t] = 1 + src[t + 1];
  __syncthreads();
  if (t == 0) {
    float m = 0.0f, sum = 0.0f;
    for (int i = T - 1; i >= 0; --i) {
      const float prec = (float)(i + 1) / (float)s_p[i];  // IEEE div, as ref
      m = fmaxf(m, prec);
      if (s_p[i] >= 2) sum += m * 0.00390625f;  // * (1/256), exact
    }
    out[0] = sum;
  }
}

extern "C" void kernel_launch(void* const* d_in, const int* in_sizes, int n_in,
                              void* d_out, int out_size, void* d_ws,
                              size_t ws_size, hipStream_t stream) {
  (void)in_sizes; (void)n_in; (void)out_size; (void)ws_size;
  const float* prop = (const float*)d_in[0];
  const float* lab  = (const float*)d_in[1];
  uint8_t* ws = (uint8_t*)d_ws;
  uint32_t* masks  = (uint32_t*)(ws + OFF_MASKS);
  uint32_t* chOR   = (uint32_t*)(ws + OFF_CHUNKOR);
  int*      tp_idx = (int*)(ws + OFF_TPIDX);
  int*      tp_cnt = (int*)(ws + OFF_TPCNT);
  unsigned long long* keys = (unsigned long long*)(ws + OFF_KEYS);
  int*      hist   = (int*)(ws + OFF_HIST);
  float*    out    = (float*)d_out;

  k_masks<<<dim3(NCHUNK), dim3(256), 0, stream>>>(prop, lab, masks, chOR, hist);
  k_scan <<<dim3(1),      dim3(64),  0, stream>>>(masks, chOR, tp_idx, tp_cnt);
  k_sort <<<dim3(1),      dim3(256), 0, stream>>>(prop, tp_idx, tp_cnt, keys);
  k_rank <<<dim3(NCHUNK), dim3(256), 0, stream>>>(prop, keys, hist);
  k_ap   <<<dim3(1),      dim3(256), 0, stream>>>(tp_cnt, hist, out);
}